// Round 3
// baseline (15367.172 us; speedup 1.0000x reference)
//
#include <hip/hip_runtime.h>
#include <hip/hip_cooperative_groups.h>
#include <math.h>

namespace cg = cooperative_groups;

// ---------------- problem constants ----------------
// B=64, P=196, H=E=A=512, V=10000, T=49, gates=2048, Kx=1536

// ---------------- ws layout (float element offsets) ----------------
#define WS_SORT   0             // int[64]
#define WS_DL     64            // int[64]
#define WS_NB     128           // int[64]: nb[0..48], [49]=R
#define WS_ROWOFF 192           // int[64] (50 used)
#define WS_CAPS   256           // int[64*50]
#define WS_RMAP   3456          // int[3136]
#define WS_H      6592          // float[64*512]
#define WS_C      39360         // float[64*512]
#define WS_ATT2   72128         // float[64*512]
#define WS_E      104896        // float[64*200] exp(e)
#define WS_Z      117696        // float[8][64]
#define WS_CTXP   118208        // float[8][64][512]
#define WS_PG     380352        // float[32][64][2048] gate partials (loop only)
#define WS_WSH    380352        // half[10000*512] overlays WS_PG (post-loop)
#define WS_HALLH  4574656       // half[3136*512]
#define WS_ENC    5377472       // half[12544*512]
// end = 8,588,736 floats = 34.4 MB

// ---------------- out layout (floats) ----------------
#define OUT_SCORES 0
#define OUT_CAPS   31360000
#define OUT_DL     31363200
#define OUT_W      31363264
#define OUT_SORT   31977920

typedef _Float16 half8 __attribute__((ext_vector_type(8)));
typedef _Float16 half4 __attribute__((ext_vector_type(4)));
typedef float floatx4 __attribute__((ext_vector_type(4)));

__device__ __forceinline__ float sigm(float x) { return 1.f / (1.f + expf(-x)); }

__device__ __forceinline__ float wave_reduce_sum(float v) {
#pragma unroll
  for (int off = 32; off; off >>= 1) v += __shfl_down(v, off);
  return v;
}

// ---------------- fp32 GEMM cores (64x64 tile per wave, 8x8 micro) ----------------
__device__ __forceinline__ void gemm_acc32(const float* __restrict__ As, const float* __restrict__ Bs,
                                           float acc[8][8], int tx, int ty) {
#pragma unroll 8
  for (int kk = 0; kk < 32; ++kk) {
    const float4* ar = (const float4*)(As + kk * 68 + tx * 8);
    const float4* br = (const float4*)(Bs + kk * 68 + ty * 8);
    float4 a0 = ar[0], a1 = ar[1];
    float4 b0 = br[0], b1 = br[1];
    float av[8] = {a0.x, a0.y, a0.z, a0.w, a1.x, a1.y, a1.z, a1.w};
    float bv[8] = {b0.x, b0.y, b0.z, b0.w, b1.x, b1.y, b1.z, b1.w};
#pragma unroll
    for (int i = 0; i < 8; ++i)
#pragma unroll
      for (int j = 0; j < 8; ++j)
        acc[i][j] = fmaf(av[i], bv[j], acc[i][j]);
  }
}

__device__ __forceinline__ void gemm_acc16(const float* __restrict__ As, const float* __restrict__ Bs,
                                           float acc[8][8], int tx, int ty) {
#pragma unroll 8
  for (int kk = 0; kk < 16; ++kk) {
    const float4* ar = (const float4*)(As + kk * 68 + tx * 8);
    const float4* br = (const float4*)(Bs + kk * 68 + ty * 8);
    float4 a0 = ar[0], a1 = ar[1];
    float4 b0 = br[0], b1 = br[1];
    float av[8] = {a0.x, a0.y, a0.z, a0.w, a1.x, a1.y, a1.z, a1.w};
    float bv[8] = {b0.x, b0.y, b0.z, b0.w, b1.x, b1.y, b1.z, b1.w};
#pragma unroll
    for (int i = 0; i < 8; ++i)
#pragma unroll
      for (int j = 0; j < 8; ++j)
        acc[i][j] = fmaf(av[i], bv[j], acc[i][j]);
  }
}

// 64x32 tile loaders for the (64-thread) encatt kernel
__device__ __forceinline__ void load_tile_strided(const float* __restrict__ src, int row0, int ld, int k0,
                                                  float* __restrict__ dst, int tid, int nrows_valid) {
#pragma unroll
  for (int i = 0; i < 8; ++i) {
    int lin = tid + 64 * i;
    int m = lin >> 3, kf = lin & 7;
    float4 v = make_float4(0.f, 0.f, 0.f, 0.f);
    if (m < nrows_valid) v = *(const float4*)(src + (long)(row0 + m) * ld + k0 + kf * 4);
    dst[(kf * 4 + 0) * 68 + m] = v.x;
    dst[(kf * 4 + 1) * 68 + m] = v.y;
    dst[(kf * 4 + 2) * 68 + m] = v.z;
    dst[(kf * 4 + 3) * 68 + m] = v.w;
  }
}

__device__ __forceinline__ void load_tile_gather(const float* __restrict__ src, const int* __restrict__ bases,
                                                 int k0, float* __restrict__ dst, int tid) {
#pragma unroll
  for (int i = 0; i < 8; ++i) {
    int lin = tid + 64 * i;
    int m = lin >> 3, kf = lin & 7;
    float4 v = *(const float4*)(src + bases[m] + k0 + kf * 4);
    dst[(kf * 4 + 0) * 68 + m] = v.x;
    dst[(kf * 4 + 1) * 68 + m] = v.y;
    dst[(kf * 4 + 2) * 68 + m] = v.z;
    dst[(kf * 4 + 3) * 68 + m] = v.w;
  }
}

// ---------------- setup ----------------
__global__ __launch_bounds__(64) void setup_kernel(const int* __restrict__ caps, const int* __restrict__ caplens,
                                                   float* __restrict__ ws, float* __restrict__ out) {
  __shared__ int cl_s[64], so_s[64], dl_s[64], nb_s[49], ro_s[50];
  int i = threadIdx.x;
  cl_s[i] = caplens[i];
  __syncthreads();
  int cli = cl_s[i];
  int r = 0;
  for (int j = 0; j < 64; ++j) {
    int clj = cl_s[j];
    r += (clj > cli) || (clj == cli && j < i);   // stable descending
  }
  so_s[r] = i;
  dl_s[r] = cli - 1;
  __syncthreads();
  int* iws = (int*)ws;
  iws[WS_SORT + i] = so_s[i];
  iws[WS_DL + i] = dl_s[i];
  out[OUT_SORT + i] = (float)so_s[i];
  out[OUT_DL + i] = (float)dl_s[i];
  if (i < 49) {
    int n = 0;
    for (int b = 0; b < 64; ++b) n += (dl_s[b] > i);
    iws[WS_NB + i] = n;
    nb_s[i] = n;
  }
  __syncthreads();
  if (i == 0) {
    int acc = 0;
    for (int t = 0; t < 49; ++t) { ro_s[t] = acc; acc += nb_s[t]; }
    ro_s[49] = acc;
    iws[WS_NB + 49] = acc;
  }
  __syncthreads();
  if (i < 50) iws[WS_ROWOFF + i] = ro_s[i];
  int R = ro_s[49];
  for (int rr = i; rr < 3136; rr += 64) {
    int val = 0;
    if (rr < R) {
      int t = 0;
      while (t < 48 && ro_s[t + 1] <= rr) ++t;
      val = t * 64 + (rr - ro_s[t]);
    }
    iws[WS_RMAP + rr] = val;
  }
  for (int j = i; j < 3200; j += 64) {
    int k = j / 50, jj = j - k * 50;
    int cv = caps[so_s[k] * 50 + jj];
    iws[WS_CAPS + j] = cv;
    out[OUT_CAPS + j] = (float)cv;
  }
}

// ---------------- zero scores+weights+h/c, att2 = b_dec ----------------
__global__ void zero_init_kernel(float* __restrict__ out, float* __restrict__ ws, const float* __restrict__ b_dec) {
  const float4 z = make_float4(0.f, 0.f, 0.f, 0.f);
  float4* out4 = (float4*)out;
  float4* ws4 = (float4*)ws;
  const float4* bd4 = (const float4*)b_dec;
  for (long idx = (long)blockIdx.x * 256 + threadIdx.x; idx < 8012096L; idx += (long)gridDim.x * 256) {
    if (idx < 7840000L) {
      out4[idx] = z;                                   // scores
    } else if (idx < 7993664L) {
      out4[7840816L + (idx - 7840000L)] = z;           // weights
    } else if (idx < 8010048L) {
      ws4[1648L + (idx - 7993664L)] = z;               // h, c
    } else {
      long j = idx - 8010048L;
      ws4[18032L + j] = bd4[j & 127];                  // att2 = b_dec
    }
  }
}

// ---------------- enc_att = feats_sorted @ W_enc^T + b_enc -> fp16 ----------------
__global__ __launch_bounds__(64) void encatt_kernel(const float* __restrict__ image, const float* __restrict__ W_enc,
                                                    const float* __restrict__ b_enc, float* __restrict__ ws) {
  __shared__ __align__(16) float As[32 * 68];
  __shared__ __align__(16) float Bs[32 * 68];
  __shared__ int rb[64];
  int tid = threadIdx.x;
  const int* iws = (const int*)ws;
  int mt = blockIdx.x, nt = blockIdx.y;
  {
    int r = mt * 64 + tid;
    int b = r / 196;
    int p = r - b * 196;
    rb[tid] = iws[WS_SORT + b] * 100352 + p * 512;
  }
  float acc[8][8] = {};
  for (int ch = 0; ch < 16; ++ch) {
    __syncthreads();
    load_tile_gather(image, rb, ch * 32, As, tid);
    load_tile_strided(W_enc, nt * 64, 512, ch * 32, Bs, tid, 64);
    __syncthreads();
    gemm_acc32(As, Bs, acc, tid & 7, tid >> 3);
  }
  int tx = tid & 7, ty = tid >> 3;
  int r0 = mt * 64 + tx * 8;
  int n0 = nt * 64 + ty * 8;
  _Float16* encH = (_Float16*)(ws + WS_ENC);
#pragma unroll
  for (int i = 0; i < 8; ++i) {
    half8 hv;
#pragma unroll
    for (int q = 0; q < 8; ++q) hv[q] = (_Float16)(acc[i][q] + b_enc[n0 + q]);
    *(half8*)(encH + (long)(r0 + i) * 512 + n0) = hv;
  }
}

// ---------------- persistent cooperative loop kernel ----------------
__global__ __launch_bounds__(256, 2) void loop_kernel(
    float* __restrict__ ws, const float* __restrict__ image, const float* __restrict__ emb,
    const float* __restrict__ W_ih, const float* __restrict__ W_hh,
    const float* __restrict__ b_ih, const float* __restrict__ b_hh,
    const float* __restrict__ W_dec, const float* __restrict__ b_dec,
    const float* __restrict__ W_full, const float* __restrict__ b_full,
    float* __restrict__ out) {
  cg::grid_group grid = cg::this_grid();
  __shared__ __align__(16) float smem[8832];
  int* iws = (int*)ws;
  const int bl = blockIdx.x;
  const int tid = threadIdx.x;
  const int wv = tid >> 6, lane = tid & 63;

  for (int t = 0; t < 49; ++t) {
    // ======== Phase A: e = relu(enc+att2)@W_full -> exp, Z partial, ctx partial ========
    {
      int b = bl >> 3, pg = bl & 7;
      int nb = iws[WS_NB + t];
      if (b < nb) {
        float* att2_s = smem;
        float* wf_s = smem + 512;
        float* e_s = smem + 1024;   // 25 used
        float* zp = smem + 1056;    // 4
        for (int a = tid; a < 512; a += 256) {
          att2_s[a] = ws[WS_ATT2 + b * 512 + a];
          wf_s[a] = W_full[a];
        }
        __syncthreads();
        const _Float16* encH = (const _Float16*)(ws + WS_ENC);
        float bf0 = b_full[0];
        float zloc = 0.f;
        const float4 at0 = *(const float4*)(att2_s + lane * 8);
        const float4 at1 = *(const float4*)(att2_s + lane * 8 + 4);
        const float4 wf0 = *(const float4*)(wf_s + lane * 8);
        const float4 wf1 = *(const float4*)(wf_s + lane * 8 + 4);
        for (int i = wv; i < 25; i += 4) {
          int p = pg + 8 * i;
          if (p < 196) {
            const half8 ev8 = *(const half8*)(encH + (long)(b * 196 + p) * 512 + lane * 8);
            float acc;
            acc = fmaxf((float)ev8[0] + at0.x, 0.f) * wf0.x;
            acc = fmaf(fmaxf((float)ev8[1] + at0.y, 0.f), wf0.y, acc);
            acc = fmaf(fmaxf((float)ev8[2] + at0.z, 0.f), wf0.z, acc);
            acc = fmaf(fmaxf((float)ev8[3] + at0.w, 0.f), wf0.w, acc);
            acc = fmaf(fmaxf((float)ev8[4] + at1.x, 0.f), wf1.x, acc);
            acc = fmaf(fmaxf((float)ev8[5] + at1.y, 0.f), wf1.y, acc);
            acc = fmaf(fmaxf((float)ev8[6] + at1.z, 0.f), wf1.z, acc);
            acc = fmaf(fmaxf((float)ev8[7] + at1.w, 0.f), wf1.w, acc);
            acc = wave_reduce_sum(acc);
            if (lane == 0) {
              float ev = expf(acc + bf0);   // |e| small by construction; no max-sub needed
              e_s[i] = ev;
              zloc += ev;
            }
          }
        }
        if (lane == 0) zp[wv] = zloc;
        __syncthreads();
        if (tid == 0) ws[WS_Z + pg * 64 + b] = zp[0] + zp[1] + zp[2] + zp[3];
        if (tid < 25) {
          int p = pg + 8 * tid;
          if (p < 196) ws[WS_E + b * 200 + p] = e_s[tid];
        }
        long sb = (long)iws[WS_SORT + b] * 100352;
        float a0 = 0.f, a1 = 0.f;
        for (int i = 0; i < 25; ++i) {
          int p = pg + 8 * i;
          if (p < 196) {
            float ev = e_s[i];
            const float* fp = image + sb + (long)p * 512;
            a0 = fmaf(ev, fp[tid], a0);
            a1 = fmaf(ev, fp[tid + 256], a1);
          }
        }
        ws[WS_CTXP + pg * 32768 + b * 512 + tid] = a0;
        ws[WS_CTXP + pg * 32768 + b * 512 + 256 + tid] = a1;
      }
    }
    grid.sync();
    // ======== Phase B: gates = [emb|ctx|h] @ [W_ih;W_hh]^T, 32x32 wave-tiles ========
    {
      int* rbe_s = (int*)smem;            // [64]
      float* rz_s = smem + 64;            // [64]
      if (tid < 64) {
        rbe_s[tid] = iws[WS_CAPS + tid * 50 + t] * 512;
      } else if (tid < 128) {
        int b = tid - 64;
        float z = 0.f;
#pragma unroll
        for (int s = 0; s < 8; ++s) z += ws[WS_Z + s * 64 + b];
        rz_s[b] = 1.f / z;
      }
      __syncthreads();
      if (wv < 2) {
        int tau = bl * 2 + wv;            // 0..1023
        int nt = tau >> 5, ks = tau & 31; // nt: 64 cols, ks: K=48
        float* As = smem + 128 + wv * 2176;
        float* Bs = As + 1088;
        float acc[8][8] = {};
        for (int ch = 0; ch < 3; ++ch) {
          int k0 = ks * 48 + ch * 16;
          asm volatile("s_waitcnt lgkmcnt(0)" ::: "memory");
          // A tile: 64 rows x 16 k -> As[k][m]
#pragma unroll
          for (int it = 0; it < 4; ++it) {
            int lin = lane + 64 * it;
            int m = lin >> 2, kf = lin & 3;
            float4 v;
            if (k0 < 512) {
              v = *(const float4*)(emb + rbe_s[m] + k0 + kf * 4);
            } else if (k0 < 1024) {
              const float* base = ws + WS_CTXP + m * 512 + (k0 - 512) + kf * 4;
              float4 v0 = *(const float4*)(base);
              float4 v1 = *(const float4*)(base + 32768);
              float4 v2 = *(const float4*)(base + 65536);
              float4 v3 = *(const float4*)(base + 98304);
              float4 v4 = *(const float4*)(base + 131072);
              float4 v5 = *(const float4*)(base + 163840);
              float4 v6 = *(const float4*)(base + 196608);
              float4 v7 = *(const float4*)(base + 229376);
              float rz = rz_s[m];
              v.x = (v0.x + v1.x + v2.x + v3.x + v4.x + v5.x + v6.x + v7.x) * rz;
              v.y = (v0.y + v1.y + v2.y + v3.y + v4.y + v5.y + v6.y + v7.y) * rz;
              v.z = (v0.z + v1.z + v2.z + v3.z + v4.z + v5.z + v6.z + v7.z) * rz;
              v.w = (v0.w + v1.w + v2.w + v3.w + v4.w + v5.w + v6.w + v7.w) * rz;
            } else {
              v = *(const float4*)(ws + WS_H + m * 512 + (k0 - 1024) + kf * 4);
            }
            As[(kf * 4 + 0) * 68 + m] = v.x;
            As[(kf * 4 + 1) * 68 + m] = v.y;
            As[(kf * 4 + 2) * 68 + m] = v.z;
            As[(kf * 4 + 3) * 68 + m] = v.w;
          }
          // B tile: 64 rows (cols of gates) x 16 k
#pragma unroll
          for (int it = 0; it < 4; ++it) {
            int lin = lane + 64 * it;
            int n = lin >> 2, kf = lin & 3;
            float4 v;
            if (k0 < 1024) v = *(const float4*)(W_ih + (long)(nt * 64 + n) * 1024 + k0 + kf * 4);
            else           v = *(const float4*)(W_hh + (long)(nt * 64 + n) * 512 + (k0 - 1024) + kf * 4);
            Bs[(kf * 4 + 0) * 68 + n] = v.x;
            Bs[(kf * 4 + 1) * 68 + n] = v.y;
            Bs[(kf * 4 + 2) * 68 + n] = v.z;
            Bs[(kf * 4 + 3) * 68 + n] = v.w;
          }
          asm volatile("s_waitcnt lgkmcnt(0)" ::: "memory");
          gemm_acc16(As, Bs, acc, lane & 7, lane >> 3);
        }
        int tx = lane & 7, ty = lane >> 3;
        float* pgp = ws + WS_PG + ks * 131072;
        int j0 = nt * 64 + ty * 8;
#pragma unroll
        for (int i = 0; i < 8; ++i) {
          int br = tx * 8 + i;
          float* cp = pgp + br * 2048 + j0;
          *(float4*)(cp)     = make_float4(acc[i][0], acc[i][1], acc[i][2], acc[i][3]);
          *(float4*)(cp + 4) = make_float4(acc[i][4], acc[i][5], acc[i][6], acc[i][7]);
        }
      }
    }
    grid.sync();
    // ======== Phase C: lstm cell + HALL(fp16) + weights out ========
    {
      int nb = iws[WS_NB + t];
      if (bl < 128) {
        int b = bl >> 1, hs = bl & 1;
        int d = hs * 256 + tid;
        float gi = b_ih[d] + b_hh[d];
        float gf = b_ih[512 + d] + b_hh[512 + d];
        float gg = b_ih[1024 + d] + b_hh[1024 + d];
        float go = b_ih[1536 + d] + b_hh[1536 + d];
        const float* pgp = ws + WS_PG + b * 2048;
#pragma unroll
        for (int ks = 0; ks < 32; ++ks) {
          const float* p = pgp + ks * 131072;
          gi += p[d]; gf += p[512 + d]; gg += p[1024 + d]; go += p[1536 + d];
        }
        float c = ws[WS_C + b * 512 + d];
        float cn = sigm(gf) * c + sigm(gi) * tanhf(gg);
        float hn = sigm(go) * tanhf(cn);
        if (b < nb) {
          ws[WS_C + b * 512 + d] = cn;
          ws[WS_H + b * 512 + d] = hn;
          ((_Float16*)(ws + WS_HALLH))[(long)(iws[WS_ROWOFF + t] + b) * 512 + d] = (_Float16)hn;
        }
      } else if (bl < 384) {
        int u = bl - 128;
        int b = u >> 2, q = u & 3;
        if (b < nb && tid < 49) {
          float z = 0.f;
#pragma unroll
          for (int s = 0; s < 8; ++s) z += ws[WS_Z + s * 64 + b];
          int p = q * 49 + tid;
          out[OUT_W + (long)(b * 49 + t) * 196 + p] = ws[WS_E + b * 200 + p] / z;
        }
      }
    }
    grid.sync();
    // ======== Phase D: att2(t+1) = h @ W_dec^T + b_dec ========
    if (t < 48) {
      int b = bl >> 3, as = bl & 7;
      int nbn = iws[WS_NB + t + 1];
      if (b < nbn) {
        float* h_s = smem;
        for (int a = tid; a < 512; a += 256) h_s[a] = ws[WS_H + b * 512 + a];
        __syncthreads();
        const float4 h0 = *(const float4*)(h_s + lane * 8);
        const float4 h1 = *(const float4*)(h_s + lane * 8 + 4);
        for (int j = 0; j < 16; ++j) {
          int a = as * 64 + wv * 16 + j;
          const float* wd = W_dec + (long)a * 512 + lane * 8;
          float4 w0 = *(const float4*)(wd);
          float4 w1 = *(const float4*)(wd + 4);
          float acc = w0.x * h0.x;
          acc = fmaf(w0.y, h0.y, acc);
          acc = fmaf(w0.z, h0.z, acc);
          acc = fmaf(w0.w, h0.w, acc);
          acc = fmaf(w1.x, h1.x, acc);
          acc = fmaf(w1.y, h1.y, acc);
          acc = fmaf(w1.z, h1.z, acc);
          acc = fmaf(w1.w, h1.w, acc);
          acc = wave_reduce_sum(acc);
          if (lane == 0) ws[WS_ATT2 + b * 512 + a] = acc + b_dec[a];
        }
      }
      grid.sync();
    }
  }
}

// ---------------- W_score fp32 -> fp16 (into WS_PG overlay, after loop) ----------------
__global__ void w2h_kernel(const float* __restrict__ W, float* __restrict__ ws) {
  _Float16* dst = (_Float16*)(ws + WS_WSH);
  int i = blockIdx.x * 256 + threadIdx.x;   // float4 index; 10000*512/4 = 1,280,000
  if (i < 1280000) {
    float4 v = ((const float4*)W)[i];
    half4 h;
    h[0] = (_Float16)v.x; h[1] = (_Float16)v.y; h[2] = (_Float16)v.z; h[3] = (_Float16)v.w;
    *(half4*)(dst + i * 4) = h;
  }
}

// ---------------- scores = HALL(fp16) @ W_score(fp16)^T + b_score, MFMA ----------------
__global__ __launch_bounds__(256) void score_mfma_kernel(const float* __restrict__ ws,
                                                         const float* __restrict__ b_score,
                                                         float* __restrict__ out) {
  const int* iws = (const int*)ws;
  int R = iws[WS_NB + 49];
  int mt = blockIdx.x, nt = blockIdx.y;
  if (mt * 128 >= R) return;
  int tid = threadIdx.x;
  int wv = tid >> 6, lane = tid & 63;
  int m0 = mt * 128 + (wv & 1) * 64;
  int n0 = nt * 128 + (wv >> 1) * 64;
  int r16 = lane & 15, quad = lane >> 4;
  const _Float16* AH = (const _Float16*)(ws + WS_HALLH);
  const _Float16* BH = (const _Float16*)(ws + WS_WSH);
  floatx4 acc[4][4];
#pragma unroll
  for (int i = 0; i < 4; ++i)
#pragma unroll
    for (int j = 0; j < 4; ++j) acc[i][j] = (floatx4){0.f, 0.f, 0.f, 0.f};
#pragma unroll 4
  for (int kc = 0; kc < 16; ++kc) {
    int ko = kc * 32 + quad * 8;
    half8 a[4], b[4];
#pragma unroll
    for (int i = 0; i < 4; ++i) a[i] = *(const half8*)(AH + (long)(m0 + i * 16 + r16) * 512 + ko);
#pragma unroll
    for (int j = 0; j < 4; ++j) b[j] = *(const half8*)(BH + (long)(n0 + j * 16 + r16) * 512 + ko);
#pragma unroll
    for (int i = 0; i < 4; ++i)
#pragma unroll
      for (int j = 0; j < 4; ++j)
        acc[i][j] = __builtin_amdgcn_mfma_f32_16x16x32_f16(a[i], b[j], acc[i][j], 0, 0, 0);
  }
  // C/D layout: col = lane&15, row = quad*4 + reg  (dtype-independent, verified)
#pragma unroll
  for (int i = 0; i < 4; ++i) {
    int rbase = m0 + i * 16 + quad * 4;
#pragma unroll
    for (int r = 0; r < 4; ++r) {
      int grow = rbase + r;
      if (grow < R) {
        int tb = iws[WS_RMAP + grow];
        long obase = (long)(tb & 63) * 490000 + (long)(tb >> 6) * 10000;
#pragma unroll
        for (int j = 0; j < 4; ++j) {
          int col = n0 + j * 16 + r16;
          if (col < 10000) out[obase + col] = acc[i][j][r] + b_score[col];
        }
      }
    }
  }
}

// ---------------- launch ----------------
extern "C" void kernel_launch(void* const* d_in, const int* in_sizes, int n_in,
                              void* d_out, int out_size, void* d_ws, size_t ws_size,
                              hipStream_t stream) {
  const float* image   = (const float*)d_in[0];
  const int*   caps    = (const int*)d_in[1];
  const int*   caplens = (const int*)d_in[2];
  const float* emb     = (const float*)d_in[3];
  const float* W_ih    = (const float*)d_in[4];
  const float* W_hh    = (const float*)d_in[5];
  const float* b_ih    = (const float*)d_in[6];
  const float* b_hh    = (const float*)d_in[7];
  const float* W_enc   = (const float*)d_in[8];
  const float* b_enc   = (const float*)d_in[9];
  const float* W_dec   = (const float*)d_in[10];
  const float* b_dec   = (const float*)d_in[11];
  const float* W_full  = (const float*)d_in[12];
  const float* b_full  = (const float*)d_in[13];
  const float* W_score = (const float*)d_in[14];
  const float* b_score = (const float*)d_in[15];
  float* out = (float*)d_out;
  float* ws  = (float*)d_ws;

  setup_kernel<<<1, 64, 0, stream>>>(caps, caplens, ws, out);
  zero_init_kernel<<<2048, 256, 0, stream>>>(out, ws, b_dec);
  encatt_kernel<<<dim3(196, 8), 64, 0, stream>>>(image, W_enc, b_enc, ws);

  void* args[] = {(void*)&ws, (void*)&image, (void*)&emb, (void*)&W_ih, (void*)&W_hh,
                  (void*)&b_ih, (void*)&b_hh, (void*)&W_dec, (void*)&b_dec,
                  (void*)&W_full, (void*)&b_full, (void*)&out};
  hipLaunchCooperativeKernel((void*)loop_kernel, dim3(512), dim3(256), args, 0, stream);

  w2h_kernel<<<5000, 256, 0, stream>>>(W_score, ws);
  score_mfma_kernel<<<dim3(25, 79), 256, 0, stream>>>(ws, b_score, out);
}

// Round 4
// 3685.983 us; speedup vs baseline: 4.1691x; 4.1691x over previous
//
#include <hip/hip_runtime.h>
#include <math.h>

// ---------------- problem constants ----------------
// B=64, P=196, H=E=A=512, V=10000, T=49, gates=2048 (W_ih: 2048x1024, W_hh: 2048x512)

// ---------------- ws layout (float element offsets) ----------------
#define WS_SORT   0             // int[64]
#define WS_DL     64            // int[64]
#define WS_NB     128           // int[64]: nb[0..48], [49]=R
#define WS_ROWOFF 192           // int[50]
#define WS_CAPS   256           // int[64*50]
#define WS_RMAP   3456          // int[3136]
#define WS_EROW   6592          // int[3136]: emb row base (cap*512) for m=b*49+t
#define WS_H      9728          // float[64*512]
#define WS_C      42496         // float[64*512]
#define WS_CTX    75264         // float[64*512] (normalized ctx)
#define WS_WDECH  108032        // half[512*512]  (131072 floats)
#define WS_GEMB   239104        // float[3136*2048] emb@W_ih_emb^T partial gates
#define WS_WSH    239104        // half[10000*512] overlays WS_GEMB post-loop
#define WS_HALLH  6661632       // half[3136*512] compact h rows
#define WS_ENCH   7464448       // half[12544*512] enc_att
// end = 10,675,712 floats = 42.7 MB

// ---------------- out layout (floats) ----------------
#define OUT_SCORES 0
#define OUT_CAPS   31360000
#define OUT_DL     31363200
#define OUT_W      31363264
#define OUT_SORT   31977920

typedef _Float16 half8 __attribute__((ext_vector_type(8)));
typedef _Float16 half4 __attribute__((ext_vector_type(4)));
typedef float floatx4 __attribute__((ext_vector_type(4)));

__device__ __forceinline__ float sigm(float x) { return 1.f / (1.f + expf(-x)); }

__device__ __forceinline__ float wave_reduce_sum(float v) {
#pragma unroll
  for (int off = 32; off; off >>= 1) v += __shfl_down(v, off);
  return v;
}

// ---------------- setup ----------------
__global__ __launch_bounds__(64) void setup_kernel(const int* __restrict__ caps, const int* __restrict__ caplens,
                                                   float* __restrict__ ws, float* __restrict__ out) {
  __shared__ int cl_s[64], so_s[64], dl_s[64], nb_s[49], ro_s[50];
  int i = threadIdx.x;
  cl_s[i] = caplens[i];
  __syncthreads();
  int cli = cl_s[i];
  int r = 0;
  for (int j = 0; j < 64; ++j) {
    int clj = cl_s[j];
    r += (clj > cli) || (clj == cli && j < i);   // stable descending
  }
  so_s[r] = i;
  dl_s[r] = cli - 1;
  __syncthreads();
  int* iws = (int*)ws;
  iws[WS_SORT + i] = so_s[i];
  iws[WS_DL + i] = dl_s[i];
  out[OUT_SORT + i] = (float)so_s[i];
  out[OUT_DL + i] = (float)dl_s[i];
  if (i < 49) {
    int n = 0;
    for (int b = 0; b < 64; ++b) n += (dl_s[b] > i);
    iws[WS_NB + i] = n;
    nb_s[i] = n;
  }
  __syncthreads();
  if (i == 0) {
    int acc = 0;
    for (int t = 0; t < 49; ++t) { ro_s[t] = acc; acc += nb_s[t]; }
    ro_s[49] = acc;
    iws[WS_NB + 49] = acc;
  }
  __syncthreads();
  if (i < 50) iws[WS_ROWOFF + i] = ro_s[i];
  int R = ro_s[49];
  for (int rr = i; rr < 3136; rr += 64) {
    int val = 0;
    if (rr < R) {
      int t = 0;
      while (t < 48 && ro_s[t + 1] <= rr) ++t;
      val = t * 64 + (rr - ro_s[t]);
    }
    iws[WS_RMAP + rr] = val;
    // EROW: m = b*49+t  ->  emb row base of caps_s[b][t]
    int b = rr / 49, tt = rr - b * 49;
    iws[WS_EROW + rr] = caps[so_s[b] * 50 + tt] * 512;
  }
  for (int j = i; j < 3200; j += 64) {
    int k = j / 50, jj = j - k * 50;
    int cv = caps[so_s[k] * 50 + jj];
    iws[WS_CAPS + j] = cv;
    out[OUT_CAPS + j] = (float)cv;
  }
}

// ---------------- zero scores+weights+h/c ----------------
__global__ void zero_init_kernel(float* __restrict__ out, float* __restrict__ ws) {
  const float4 z = make_float4(0.f, 0.f, 0.f, 0.f);
  float4* out4 = (float4*)out;
  float4* ws4 = (float4*)ws;
  for (long idx = (long)blockIdx.x * 256 + threadIdx.x; idx < 8010048L; idx += (long)gridDim.x * 256) {
    if (idx < 7840000L) {
      out4[idx] = z;                                   // scores
    } else if (idx < 7993664L) {
      out4[7840816L + (idx - 7840000L)] = z;           // weights
    } else {
      ws4[2432L + (idx - 7993664L)] = z;               // h, c
    }
  }
}

// ---------------- W_dec fp32 -> fp16 ----------------
__global__ void wdech_kernel(const float* __restrict__ W, float* __restrict__ ws) {
  _Float16* dst = (_Float16*)(ws + WS_WDECH);
  int i = blockIdx.x * 256 + threadIdx.x;   // 512*512/4 = 65536 float4s
  if (i < 65536) {
    float4 v = ((const float4*)W)[i];
    half4 h;
    h[0] = (_Float16)v.x; h[1] = (_Float16)v.y; h[2] = (_Float16)v.z; h[3] = (_Float16)v.w;
    *(half4*)(dst + i * 4) = h;
  }
}

// ---------------- enc_att = feats_sorted @ W_enc^T + b_enc -> fp16 (fp32 compute) ----------------
__global__ __launch_bounds__(64) void encatt_kernel(const float* __restrict__ image, const float* __restrict__ W_enc,
                                                    const float* __restrict__ b_enc, float* __restrict__ ws) {
  __shared__ __align__(16) float As[32 * 68];
  __shared__ __align__(16) float Bs[32 * 68];
  __shared__ int rb[64];
  int tid = threadIdx.x;
  const int* iws = (const int*)ws;
  int mt = blockIdx.x, nt = blockIdx.y;
  {
    int r = mt * 64 + tid;
    int b = r / 196;
    int p = r - b * 196;
    rb[tid] = iws[WS_SORT + b] * 100352 + p * 512;
  }
  float acc[8][8] = {};
  for (int ch = 0; ch < 16; ++ch) {
    __syncthreads();
#pragma unroll
    for (int i = 0; i < 8; ++i) {
      int lin = tid + 64 * i;
      int m = lin >> 3, kf = lin & 7;
      float4 v = *(const float4*)(image + rb[m] + ch * 32 + kf * 4);
      As[(kf * 4 + 0) * 68 + m] = v.x;
      As[(kf * 4 + 1) * 68 + m] = v.y;
      As[(kf * 4 + 2) * 68 + m] = v.z;
      As[(kf * 4 + 3) * 68 + m] = v.w;
    }
#pragma unroll
    for (int i = 0; i < 8; ++i) {
      int lin = tid + 64 * i;
      int m = lin >> 3, kf = lin & 7;
      float4 v = *(const float4*)(W_enc + (long)(nt * 64 + m) * 512 + ch * 32 + kf * 4);
      Bs[(kf * 4 + 0) * 68 + m] = v.x;
      Bs[(kf * 4 + 1) * 68 + m] = v.y;
      Bs[(kf * 4 + 2) * 68 + m] = v.z;
      Bs[(kf * 4 + 3) * 68 + m] = v.w;
    }
    __syncthreads();
    int tx = tid & 7, ty = tid >> 3;
#pragma unroll 8
    for (int kk = 0; kk < 32; ++kk) {
      const float4* ar = (const float4*)(As + kk * 68 + tx * 8);
      const float4* br = (const float4*)(Bs + kk * 68 + ty * 8);
      float4 a0 = ar[0], a1 = ar[1];
      float4 b0 = br[0], b1 = br[1];
      float av[8] = {a0.x, a0.y, a0.z, a0.w, a1.x, a1.y, a1.z, a1.w};
      float bv[8] = {b0.x, b0.y, b0.z, b0.w, b1.x, b1.y, b1.z, b1.w};
#pragma unroll
      for (int i = 0; i < 8; ++i)
#pragma unroll
        for (int j = 0; j < 8; ++j)
          acc[i][j] = fmaf(av[i], bv[j], acc[i][j]);
    }
  }
  int tx = tid & 7, ty = tid >> 3;
  int r0 = mt * 64 + tx * 8;
  int n0 = nt * 64 + ty * 8;
  _Float16* encH = (_Float16*)(ws + WS_ENCH);
#pragma unroll
  for (int i = 0; i < 8; ++i) {
    half8 hv;
#pragma unroll
    for (int q = 0; q < 8; ++q) hv[q] = (_Float16)(acc[i][q] + b_enc[n0 + q]);
    *(half8*)(encH + (long)(r0 + i) * 512 + n0) = hv;
  }
}

// ---------------- G_emb = emb[caps_s] @ W_ih[:, :512]^T  (fp16 MFMA, fp32 out) ----------------
__global__ __launch_bounds__(256) void embgates_kernel(float* __restrict__ ws, const float* __restrict__ emb,
                                                       const float* __restrict__ W_ih) {
  const int* iws = (const int*)ws;
  int mt = blockIdx.x, nt = blockIdx.y;   // (25, 16)
  int tid = threadIdx.x;
  int wv = tid >> 6, lane = tid & 63;
  int m0 = mt * 128 + (wv & 1) * 64;
  int n0 = nt * 128 + (wv >> 1) * 64;
  int r16 = lane & 15, quad = lane >> 4;
  long arow[4];
#pragma unroll
  for (int i = 0; i < 4; ++i) {
    int rm = m0 + i * 16 + r16;
    if (rm > 3135) rm = 3135;
    arow[i] = (long)iws[WS_EROW + rm];
  }
  floatx4 acc[4][4];
#pragma unroll
  for (int i = 0; i < 4; ++i)
#pragma unroll
    for (int j = 0; j < 4; ++j) acc[i][j] = (floatx4){0.f, 0.f, 0.f, 0.f};
#pragma unroll 2
  for (int kc = 0; kc < 16; ++kc) {
    int ko = kc * 32 + quad * 8;
    half8 a[4], b[4];
#pragma unroll
    for (int i = 0; i < 4; ++i) {
      const float* p = emb + arow[i] + ko;
      float4 v0 = *(const float4*)(p);
      float4 v1 = *(const float4*)(p + 4);
      a[i][0] = (_Float16)v0.x; a[i][1] = (_Float16)v0.y; a[i][2] = (_Float16)v0.z; a[i][3] = (_Float16)v0.w;
      a[i][4] = (_Float16)v1.x; a[i][5] = (_Float16)v1.y; a[i][6] = (_Float16)v1.z; a[i][7] = (_Float16)v1.w;
    }
#pragma unroll
    for (int j = 0; j < 4; ++j) {
      const float* p = W_ih + (long)(n0 + j * 16 + r16) * 1024 + ko;
      float4 v0 = *(const float4*)(p);
      float4 v1 = *(const float4*)(p + 4);
      b[j][0] = (_Float16)v0.x; b[j][1] = (_Float16)v0.y; b[j][2] = (_Float16)v0.z; b[j][3] = (_Float16)v0.w;
      b[j][4] = (_Float16)v1.x; b[j][5] = (_Float16)v1.y; b[j][6] = (_Float16)v1.z; b[j][7] = (_Float16)v1.w;
    }
#pragma unroll
    for (int i = 0; i < 4; ++i)
#pragma unroll
      for (int j = 0; j < 4; ++j)
        acc[i][j] = __builtin_amdgcn_mfma_f32_16x16x32_f16(a[i], b[j], acc[i][j], 0, 0, 0);
  }
#pragma unroll
  for (int i = 0; i < 4; ++i) {
    int rbase = m0 + i * 16 + quad * 4;
#pragma unroll
    for (int r = 0; r < 4; ++r) {
      int row = rbase + r;
      if (row < 3136) {
#pragma unroll
        for (int j = 0; j < 4; ++j) {
          int col = n0 + j * 16 + r16;
          ws[WS_GEMB + (long)row * 2048 + col] = acc[i][j][r];
        }
      }
    }
  }
}

// ---------------- K_A: att2 + e + softmax + weights-out + normalized ctx (per active b) ----------------
__global__ __launch_bounds__(512) void attn_kernel(float* __restrict__ ws, const float* __restrict__ image,
                                                   const float* __restrict__ W_full, const float* __restrict__ b_full,
                                                   const float* __restrict__ b_dec, float* __restrict__ out, int t) {
  const int* iws = (const int*)ws;
  int b = blockIdx.x;
  if (b >= iws[WS_NB + t]) return;
  __shared__ __align__(16) float h_s[512], wf_s[512], att2_s[512], e_s[196], zred[8];
  int tid = threadIdx.x;
  int wv = tid >> 6, lane = tid & 63;
  h_s[tid] = ws[WS_H + b * 512 + tid];
  wf_s[tid] = W_full[tid];
  __syncthreads();
  // att2[a=tid] = dot(h, W_dec[a]) + b_dec[a]   (fp16 weights)
  {
    const _Float16* wd = (const _Float16*)(ws + WS_WDECH) + (long)tid * 512;
    float acc = 0.f;
#pragma unroll 4
    for (int c = 0; c < 64; ++c) {
      half8 w8 = *(const half8*)(wd + c * 8);
      float4 ha = *(const float4*)(h_s + c * 8);
      float4 hb = *(const float4*)(h_s + c * 8 + 4);
      acc = fmaf((float)w8[0], ha.x, acc);
      acc = fmaf((float)w8[1], ha.y, acc);
      acc = fmaf((float)w8[2], ha.z, acc);
      acc = fmaf((float)w8[3], ha.w, acc);
      acc = fmaf((float)w8[4], hb.x, acc);
      acc = fmaf((float)w8[5], hb.y, acc);
      acc = fmaf((float)w8[6], hb.z, acc);
      acc = fmaf((float)w8[7], hb.w, acc);
    }
    att2_s[tid] = acc + b_dec[tid];
  }
  __syncthreads();
  // e_p = W_full . relu(enc[p] + att2) + b_full ; e_s[p] = exp(e_p)
  {
    const _Float16* encH = (const _Float16*)(ws + WS_ENCH);
    float at[8], wf[8];
#pragma unroll
    for (int q = 0; q < 8; ++q) { at[q] = att2_s[lane * 8 + q]; wf[q] = wf_s[lane * 8 + q]; }
    float bf0 = b_full[0];
    for (int i = 0; i < 25; ++i) {
      int p = wv + 8 * i;
      if (p < 196) {
        half8 ev = *(const half8*)(encH + (long)(b * 196 + p) * 512 + lane * 8);
        float acc = fmaxf((float)ev[0] + at[0], 0.f) * wf[0];
#pragma unroll
        for (int q = 1; q < 8; ++q) acc = fmaf(fmaxf((float)ev[q] + at[q], 0.f), wf[q], acc);
        acc = wave_reduce_sum(acc);
        if (lane == 0) e_s[p] = expf(acc + bf0);   // |e| small by construction; no max-sub
      }
    }
  }
  __syncthreads();
  // Z, weights out
  float v = (tid < 196) ? e_s[tid] : 0.f;
  float sr = wave_reduce_sum(v);
  if (lane == 0) zred[wv] = sr;
  __syncthreads();
  float rz = 1.f / (zred[0] + zred[1] + zred[2] + zred[3] + zred[4] + zred[5] + zred[6] + zred[7]);
  if (tid < 196) out[OUT_W + (long)(b * 49 + t) * 196 + tid] = e_s[tid] * rz;
  // ctx[d=tid] = rz * sum_p e_p * feats[p][d]
  {
    long sb = (long)iws[WS_SORT + b] * 100352;
    const float* img = image + sb;
    float acc = 0.f;
#pragma unroll 4
    for (int c = 0; c < 49; ++c) {
      float4 ev = *(const float4*)(e_s + c * 4);
      acc = fmaf(ev.x, img[(c * 4 + 0) * 512 + tid], acc);
      acc = fmaf(ev.y, img[(c * 4 + 1) * 512 + tid], acc);
      acc = fmaf(ev.z, img[(c * 4 + 2) * 512 + tid], acc);
      acc = fmaf(ev.w, img[(c * 4 + 3) * 512 + tid], acc);
    }
    ws[WS_CTX + b * 512 + tid] = acc * rz;
  }
}

// ---------------- K_B: gates (K=1024: ctx|h) + G_emb + LSTM cell, fused ----------------
// 256 blocks: block n owns d-pair {2n, 2n+1} i.e. gate cols {g*512 + 2n + dd}.
// 4 waves = 4 K-quarters of 256; W rows read via wave-uniform broadcast loads.
__global__ __launch_bounds__(256) void gates_lstm_kernel(float* __restrict__ ws,
                                                         const float* __restrict__ W_ih, const float* __restrict__ W_hh,
                                                         const float* __restrict__ b_ih, const float* __restrict__ b_hh,
                                                         int t) {
  const int* iws = (const int*)ws;
  int n = blockIdx.x;
  int tid = threadIdx.x;
  int lane = tid & 63;
  int w = __builtin_amdgcn_readfirstlane(tid >> 6);
  __shared__ __align__(16) float red[4 * 8 * 64];   // [w][j8][m]
  const float* xrow;
  const float* wr[8];
  {
    int koff = (w & 1) * 256;
    if (w < 2) {
      xrow = ws + WS_CTX + lane * 512 + koff;
#pragma unroll
      for (int g = 0; g < 4; ++g)
#pragma unroll
        for (int dd = 0; dd < 2; ++dd)
          wr[g * 2 + dd] = W_ih + (long)(g * 512 + 2 * n + dd) * 1024 + 512 + koff;
    } else {
      xrow = ws + WS_H + lane * 512 + koff;
#pragma unroll
      for (int g = 0; g < 4; ++g)
#pragma unroll
        for (int dd = 0; dd < 2; ++dd)
          wr[g * 2 + dd] = W_hh + (long)(g * 512 + 2 * n + dd) * 512 + koff;
    }
  }
  float acc8[8] = {};
#pragma unroll 4
  for (int c = 0; c < 64; ++c) {
    float4 xv = *(const float4*)(xrow + c * 4);
#pragma unroll
    for (int j8 = 0; j8 < 8; ++j8) {
      float4 wv4 = *(const float4*)(wr[j8] + c * 4);   // uniform addr -> scalar/broadcast
      acc8[j8] = fmaf(xv.x, wv4.x, acc8[j8]);
      acc8[j8] = fmaf(xv.y, wv4.y, acc8[j8]);
      acc8[j8] = fmaf(xv.z, wv4.z, acc8[j8]);
      acc8[j8] = fmaf(xv.w, wv4.w, acc8[j8]);
    }
  }
#pragma unroll
  for (int j8 = 0; j8 < 8; ++j8) red[((tid >> 6) * 8 + j8) * 64 + lane] = acc8[j8];
  __syncthreads();
  if (tid < 128) {
    int m = tid & 63, dd = tid >> 6;
    int d = 2 * n + dd;
    int nb = iws[WS_NB + t];
    float g4[4];
#pragma unroll
    for (int g = 0; g < 4; ++g) {
      int j8 = g * 2 + dd;
      float s = red[(0 * 8 + j8) * 64 + m] + red[(1 * 8 + j8) * 64 + m]
              + red[(2 * 8 + j8) * 64 + m] + red[(3 * 8 + j8) * 64 + m];
      int j = g * 512 + d;
      s += ws[WS_GEMB + (long)(m * 49 + t) * 2048 + j] + b_ih[j] + b_hh[j];
      g4[g] = s;
    }
    float c = ws[WS_C + m * 512 + d];
    float cn = sigm(g4[1]) * c + sigm(g4[0]) * tanhf(g4[2]);
    float hn = sigm(g4[3]) * tanhf(cn);
    if (m < nb) {
      ws[WS_C + m * 512 + d] = cn;
      ws[WS_H + m * 512 + d] = hn;
      ((_Float16*)(ws + WS_HALLH))[(long)(iws[WS_ROWOFF + t] + m) * 512 + d] = (_Float16)hn;
    }
  }
}

// ---------------- W_score fp32 -> fp16 (overlay on WS_GEMB, post-loop) ----------------
__global__ void w2h_kernel(const float* __restrict__ W, float* __restrict__ ws) {
  _Float16* dst = (_Float16*)(ws + WS_WSH);
  int i = blockIdx.x * 256 + threadIdx.x;   // 10000*512/4 = 1,280,000
  if (i < 1280000) {
    float4 v = ((const float4*)W)[i];
    half4 h;
    h[0] = (_Float16)v.x; h[1] = (_Float16)v.y; h[2] = (_Float16)v.z; h[3] = (_Float16)v.w;
    *(half4*)(dst + i * 4) = h;
  }
}

// ---------------- scores = HALL(fp16) @ W_score(fp16)^T + b_score, MFMA ----------------
__global__ __launch_bounds__(256) void score_mfma_kernel(const float* __restrict__ ws,
                                                         const float* __restrict__ b_score,
                                                         float* __restrict__ out) {
  const int* iws = (const int*)ws;
  int R = iws[WS_NB + 49];
  int mt = blockIdx.x, nt = blockIdx.y;
  if (mt * 128 >= R) return;
  int tid = threadIdx.x;
  int wv = tid >> 6, lane = tid & 63;
  int m0 = mt * 128 + (wv & 1) * 64;
  int n0 = nt * 128 + (wv >> 1) * 64;
  int r16 = lane & 15, quad = lane >> 4;
  const _Float16* AH = (const _Float16*)(ws + WS_HALLH);
  const _Float16* BH = (const _Float16*)(ws + WS_WSH);
  floatx4 acc[4][4];
#pragma unroll
  for (int i = 0; i < 4; ++i)
#pragma unroll
    for (int j = 0; j < 4; ++j) acc[i][j] = (floatx4){0.f, 0.f, 0.f, 0.f};
#pragma unroll 4
  for (int kc = 0; kc < 16; ++kc) {
    int ko = kc * 32 + quad * 8;
    half8 a[4], b[4];
#pragma unroll
    for (int i = 0; i < 4; ++i) a[i] = *(const half8*)(AH + (long)(m0 + i * 16 + r16) * 512 + ko);
#pragma unroll
    for (int j = 0; j < 4; ++j) b[j] = *(const half8*)(BH + (long)(n0 + j * 16 + r16) * 512 + ko);
#pragma unroll
    for (int i = 0; i < 4; ++i)
#pragma unroll
      for (int j = 0; j < 4; ++j)
        acc[i][j] = __builtin_amdgcn_mfma_f32_16x16x32_f16(a[i], b[j], acc[i][j], 0, 0, 0);
  }
#pragma unroll
  for (int i = 0; i < 4; ++i) {
    int rbase = m0 + i * 16 + quad * 4;
#pragma unroll
    for (int r = 0; r < 4; ++r) {
      int grow = rbase + r;
      if (grow < R) {
        int tb = iws[WS_RMAP + grow];
        long obase = (long)(tb & 63) * 490000 + (long)(tb >> 6) * 10000;
#pragma unroll
        for (int j = 0; j < 4; ++j) {
          int col = n0 + j * 16 + r16;
          if (col < 10000) out[obase + col] = acc[i][j][r] + b_score[col];
        }
      }
    }
  }
}

// ---------------- launch ----------------
extern "C" void kernel_launch(void* const* d_in, const int* in_sizes, int n_in,
                              void* d_out, int out_size, void* d_ws, size_t ws_size,
                              hipStream_t stream) {
  const float* image   = (const float*)d_in[0];
  const int*   caps    = (const int*)d_in[1];
  const int*   caplens = (const int*)d_in[2];
  const float* emb     = (const float*)d_in[3];
  const float* W_ih    = (const float*)d_in[4];
  const float* W_hh    = (const float*)d_in[5];
  const float* b_ih    = (const float*)d_in[6];
  const float* b_hh    = (const float*)d_in[7];
  const float* W_enc   = (const float*)d_in[8];
  const float* b_enc   = (const float*)d_in[9];
  const float* W_dec   = (const float*)d_in[10];
  const float* b_dec   = (const float*)d_in[11];
  const float* W_full  = (const float*)d_in[12];
  const float* b_full  = (const float*)d_in[13];
  const float* W_score = (const float*)d_in[14];
  const float* b_score = (const float*)d_in[15];
  float* out = (float*)d_out;
  float* ws  = (float*)d_ws;

  setup_kernel<<<1, 64, 0, stream>>>(caps, caplens, ws, out);
  zero_init_kernel<<<2048, 256, 0, stream>>>(out, ws);
  wdech_kernel<<<256, 256, 0, stream>>>(W_dec, ws);
  encatt_kernel<<<dim3(196, 8), 64, 0, stream>>>(image, W_enc, b_enc, ws);
  embgates_kernel<<<dim3(25, 16), 256, 0, stream>>>(ws, emb, W_ih);
  for (int t = 0; t < 49; ++t) {
    attn_kernel<<<64, 512, 0, stream>>>(ws, image, W_full, b_full, b_dec, out, t);
    gates_lstm_kernel<<<256, 256, 0, stream>>>(ws, W_ih, W_hh, b_ih, b_hh, t);
  }
  w2h_kernel<<<5000, 256, 0, stream>>>(W_score, ws);
  score_mfma_kernel<<<dim3(25, 79), 256, 0, stream>>>(ws, b_score, out);
}

// Round 5
// 3234.769 us; speedup vs baseline: 4.7506x; 1.1395x over previous
//
#include <hip/hip_runtime.h>
#include <math.h>

// ---------------- problem constants ----------------
// B=64, P=196, H=E=A=512, V=10000, T=49, gates=2048
// gate col order n' = d*4+g  <->  W row j = g*512+d

// ---------------- ws layout (float element offsets) ----------------
#define WS_SORT   0             // int[64]
#define WS_DL     64            // int[64]
#define WS_NB     128           // int[64]: nb[0..48], [49]=R
#define WS_ROWOFF 192           // int[50]
#define WS_CAPS   256           // int[64*50]
#define WS_RMAP   3456          // int[3136]
#define WS_EROW   6592          // int[3136]: emb row base for m=b*49+t
#define WS_BS     9728          // float[2048]: b_ih+b_hh in n' order
#define WS_C      11776         // float[64*512]
#define WS_XH     44544         // half[64*1024] = [ctx | h] per batch row
#define WS_WDT    60928         // half2[256][512]: (W_dec[a][2k],W_dec[a][2k+1]) at [k][a]
#define WS_WGH    192000        // half[2048][1024]: gates W, n' row order
#define WS_GEMB   1240576       // half[3136][2048]: emb @ W_ih[:, :512]^T, n' cols
#define WS_WSH    1240576       // overlay post-loop: half[10000*512]
#define WS_HALLH  4451840       // half[3136*512]
#define WS_ENCH   5254656       // half[12544*512]
// end = 8,465,920 floats = 33.9 MB

// ---------------- out layout (floats) ----------------
#define OUT_SCORES 0
#define OUT_CAPS   31360000
#define OUT_DL     31363200
#define OUT_W      31363264
#define OUT_SORT   31977920

typedef _Float16 f16x8 __attribute__((ext_vector_type(8)));
typedef _Float16 f16x4 __attribute__((ext_vector_type(4)));
typedef _Float16 f16x2 __attribute__((ext_vector_type(2)));
typedef float floatx4 __attribute__((ext_vector_type(4)));

__device__ __forceinline__ float sigm(float x) { return 1.f / (1.f + expf(-x)); }

__device__ __forceinline__ float wave_reduce_sum(float v) {
#pragma unroll
  for (int off = 32; off; off >>= 1) v += __shfl_down(v, off);
  return v;
}

__device__ __forceinline__ float dot2f(f16x2 a, f16x2 b, float c) {
#if defined(__has_builtin)
#if __has_builtin(__builtin_amdgcn_fdot2)
  return __builtin_amdgcn_fdot2(a, b, c, false);
#else
  return fmaf((float)a[0], (float)b[0], fmaf((float)a[1], (float)b[1], c));
#endif
#else
  return fmaf((float)a[0], (float)b[0], fmaf((float)a[1], (float)b[1], c));
#endif
}

// ---------------- setup ----------------
__global__ __launch_bounds__(64) void setup_kernel(const int* __restrict__ caps, const int* __restrict__ caplens,
                                                   float* __restrict__ ws, float* __restrict__ out) {
  __shared__ int cl_s[64], so_s[64], dl_s[64], nb_s[49], ro_s[50];
  int i = threadIdx.x;
  cl_s[i] = caplens[i];
  __syncthreads();
  int cli = cl_s[i];
  int r = 0;
  for (int j = 0; j < 64; ++j) {
    int clj = cl_s[j];
    r += (clj > cli) || (clj == cli && j < i);   // stable descending
  }
  so_s[r] = i;
  dl_s[r] = cli - 1;
  __syncthreads();
  int* iws = (int*)ws;
  iws[WS_SORT + i] = so_s[i];
  iws[WS_DL + i] = dl_s[i];
  out[OUT_SORT + i] = (float)so_s[i];
  out[OUT_DL + i] = (float)dl_s[i];
  if (i < 49) {
    int n = 0;
    for (int b = 0; b < 64; ++b) n += (dl_s[b] > i);
    iws[WS_NB + i] = n;
    nb_s[i] = n;
  }
  __syncthreads();
  if (i == 0) {
    int acc = 0;
    for (int t = 0; t < 49; ++t) { ro_s[t] = acc; acc += nb_s[t]; }
    ro_s[49] = acc;
    iws[WS_NB + 49] = acc;
  }
  __syncthreads();
  if (i < 50) iws[WS_ROWOFF + i] = ro_s[i];
  int R = ro_s[49];
  for (int rr = i; rr < 3136; rr += 64) {
    int val = 0;
    if (rr < R) {
      int t = 0;
      while (t < 48 && ro_s[t + 1] <= rr) ++t;
      val = t * 64 + (rr - ro_s[t]);
    }
    iws[WS_RMAP + rr] = val;
    int b = rr / 49, tt = rr - b * 49;
    iws[WS_EROW + rr] = caps[so_s[b] * 50 + tt] * 512;
  }
  for (int j = i; j < 3200; j += 64) {
    int k = j / 50, jj = j - k * 50;
    int cv = caps[so_s[k] * 50 + jj];
    iws[WS_CAPS + j] = cv;
    out[OUT_CAPS + j] = (float)cv;
  }
}

// ---------------- zero: inactive score/weight rows, c, xH ----------------
__global__ __launch_bounds__(256) void zero_kernel(float* __restrict__ out, float* __restrict__ ws) {
  const int* iws = (const int*)ws;
  int r = blockIdx.x, tid = threadIdx.x;
  const float4 z = make_float4(0.f, 0.f, 0.f, 0.f);
  if (r < 3136) {
    int b = r / 49, t = r - b * 49;
    if (t >= iws[WS_DL + b]) {
      float4* sp = (float4*)out + (long)(b * 49 + t) * 2500;
      for (int i = tid; i < 2500; i += 256) sp[i] = z;
      if (tid < 49) ((float4*)(out + OUT_W))[(long)(b * 49 + t) * 49 + tid] = z;
    }
  } else {
    int b = r - 3136;
    if (tid < 128) ((float4*)(ws + WS_C))[b * 128 + tid] = z;
    else           ((float4*)(ws + WS_XH))[b * 128 + (tid - 128)] = z;
  }
}

// ---------------- W_dec -> WDT2 half2 [k-pair][a] (LDS transpose) ----------------
__global__ __launch_bounds__(256) void wdecT_kernel(const float* __restrict__ W, float* __restrict__ ws) {
  __shared__ float tl[64][65];
  int a0 = blockIdx.x * 64, k0 = blockIdx.y * 64;
  int tid = threadIdx.x;
#pragma unroll
  for (int it = 0; it < 4; ++it) {
    int lin = it * 256 + tid;
    int row = lin >> 4, c4 = lin & 15;
    float4 v = *(const float4*)(W + (long)(a0 + row) * 512 + k0 + c4 * 4);
    tl[row][c4 * 4 + 0] = v.x;
    tl[row][c4 * 4 + 1] = v.y;
    tl[row][c4 * 4 + 2] = v.z;
    tl[row][c4 * 4 + 3] = v.w;
  }
  __syncthreads();
  f16x2* dst = (f16x2*)(ws + WS_WDT);
#pragma unroll
  for (int it = 0; it < 8; ++it) {
    int lin = it * 256 + tid;
    int kk = lin >> 6, al = lin & 63;
    f16x2 h;
    h[0] = (_Float16)tl[al][2 * kk];
    h[1] = (_Float16)tl[al][2 * kk + 1];
    dst[((k0 >> 1) + kk) * 512 + a0 + al] = h;
  }
}

// ---------------- pack gates weights fp16, n' order; bias sums ----------------
__global__ __launch_bounds__(256) void wgh_kernel(const float* __restrict__ W_ih, const float* __restrict__ W_hh,
                                                  const float* __restrict__ b_ih, const float* __restrict__ b_hh,
                                                  float* __restrict__ ws) {
  int n = blockIdx.x;        // n' = d*4+g
  int g = n & 3, d = n >> 2, j = g * 512 + d;
  int tid = threadIdx.x;
  int k = tid * 4;
  float4 v = (k < 512) ? *(const float4*)(W_ih + (long)j * 1024 + 512 + k)
                       : *(const float4*)(W_hh + (long)j * 512 + (k - 512));
  f16x4 h;
  h[0] = (_Float16)v.x; h[1] = (_Float16)v.y; h[2] = (_Float16)v.z; h[3] = (_Float16)v.w;
  *(f16x4*)((_Float16*)(ws + WS_WGH) + (long)n * 1024 + k) = h;
  if (tid == 0) ws[WS_BS + n] = b_ih[j] + b_hh[j];
}

// ---------------- enc_att = feats_sorted @ W_enc^T + b_enc -> ENCH fp16 (MFMA) ----------------
__global__ __launch_bounds__(256) void encatt_kernel(const float* __restrict__ image, const float* __restrict__ W_enc,
                                                     const float* __restrict__ b_enc, float* __restrict__ ws) {
  __shared__ __align__(16) _Float16 ctile[128 * 136];
  __shared__ float benc_s[128];
  const int* iws = (const int*)ws;
  int mt = blockIdx.x, nt = blockIdx.y;   // (98, 4)
  int tid = threadIdx.x;
  int wv = tid >> 6, lane = tid & 63;
  int r16 = lane & 15, quad = lane >> 4;
  int m0 = mt * 128 + (wv & 1) * 64;
  int n0 = nt * 128 + (wv >> 1) * 64;
  if (tid < 128) benc_s[tid] = b_enc[nt * 128 + tid];
  long abase[4];
#pragma unroll
  for (int i = 0; i < 4; ++i) {
    int rm = m0 + i * 16 + r16;
    int b = rm / 196, p = rm - b * 196;
    abase[i] = ((long)iws[WS_SORT + b] * 196 + p) * 512;
  }
  floatx4 acc[4][4];
#pragma unroll
  for (int i = 0; i < 4; ++i)
#pragma unroll
    for (int j = 0; j < 4; ++j) acc[i][j] = (floatx4){0.f, 0.f, 0.f, 0.f};
#pragma unroll 2
  for (int kc = 0; kc < 16; ++kc) {
    int ko = kc * 32 + quad * 8;
    f16x8 a[4], bf[4];
#pragma unroll
    for (int i = 0; i < 4; ++i) {
      const float* p = image + abase[i] + ko;
      float4 v0 = *(const float4*)(p);
      float4 v1 = *(const float4*)(p + 4);
      a[i][0] = (_Float16)v0.x; a[i][1] = (_Float16)v0.y; a[i][2] = (_Float16)v0.z; a[i][3] = (_Float16)v0.w;
      a[i][4] = (_Float16)v1.x; a[i][5] = (_Float16)v1.y; a[i][6] = (_Float16)v1.z; a[i][7] = (_Float16)v1.w;
    }
#pragma unroll
    for (int j = 0; j < 4; ++j) {
      const float* p = W_enc + (long)(n0 + j * 16 + r16) * 512 + ko;
      float4 v0 = *(const float4*)(p);
      float4 v1 = *(const float4*)(p + 4);
      bf[j][0] = (_Float16)v0.x; bf[j][1] = (_Float16)v0.y; bf[j][2] = (_Float16)v0.z; bf[j][3] = (_Float16)v0.w;
      bf[j][4] = (_Float16)v1.x; bf[j][5] = (_Float16)v1.y; bf[j][6] = (_Float16)v1.z; bf[j][7] = (_Float16)v1.w;
    }
#pragma unroll
    for (int i = 0; i < 4; ++i)
#pragma unroll
      for (int j = 0; j < 4; ++j)
        acc[i][j] = __builtin_amdgcn_mfma_f32_16x16x32_f16(a[i], bf[j], acc[i][j], 0, 0, 0);
  }
  __syncthreads();   // benc_s ready; also reuse of ctile safe
#pragma unroll
  for (int i = 0; i < 4; ++i) {
    int rl = (wv & 1) * 64 + i * 16 + quad * 4;
#pragma unroll
    for (int r = 0; r < 4; ++r)
#pragma unroll
      for (int j = 0; j < 4; ++j) {
        int cl = (wv >> 1) * 64 + j * 16 + r16;
        ctile[(rl + r) * 136 + cl] = (_Float16)(acc[i][j][r] + benc_s[cl]);
      }
  }
  __syncthreads();
  _Float16* encH = (_Float16*)(ws + WS_ENCH);
#pragma unroll
  for (int it = 0; it < 8; ++it) {
    int ch = it * 256 + tid;
    int row = ch >> 4, off = (ch & 15) * 8;
    f16x8 hv = *(f16x8*)(ctile + row * 136 + off);
    *(f16x8*)(encH + (long)(mt * 128 + row) * 512 + nt * 128 + off) = hv;
  }
}

// ---------------- G_emb = emb[caps_s] @ W_ih[:, :512]^T -> fp16, n' cols (MFMA) ----------------
__global__ __launch_bounds__(256) void embgates_kernel(float* __restrict__ ws, const float* __restrict__ emb,
                                                       const float* __restrict__ W_ih) {
  __shared__ __align__(16) _Float16 ctile[128 * 136];
  const int* iws = (const int*)ws;
  int mt = blockIdx.x, nt = blockIdx.y;   // (25, 16)
  int tid = threadIdx.x;
  int wv = tid >> 6, lane = tid & 63;
  int r16 = lane & 15, quad = lane >> 4;
  int m0 = mt * 128 + (wv & 1) * 64;
  int n0 = nt * 128 + (wv >> 1) * 64;
  long arow[4];
#pragma unroll
  for (int i = 0; i < 4; ++i) {
    int rm = m0 + i * 16 + r16;
    if (rm > 3135) rm = 3135;
    arow[i] = (long)iws[WS_EROW + rm];
  }
  floatx4 acc[4][4];
#pragma unroll
  for (int i = 0; i < 4; ++i)
#pragma unroll
    for (int j = 0; j < 4; ++j) acc[i][j] = (floatx4){0.f, 0.f, 0.f, 0.f};
#pragma unroll 2
  for (int kc = 0; kc < 16; ++kc) {
    int ko = kc * 32 + quad * 8;
    f16x8 a[4], bf[4];
#pragma unroll
    for (int i = 0; i < 4; ++i) {
      const float* p = emb + arow[i] + ko;
      float4 v0 = *(const float4*)(p);
      float4 v1 = *(const float4*)(p + 4);
      a[i][0] = (_Float16)v0.x; a[i][1] = (_Float16)v0.y; a[i][2] = (_Float16)v0.z; a[i][3] = (_Float16)v0.w;
      a[i][4] = (_Float16)v1.x; a[i][5] = (_Float16)v1.y; a[i][6] = (_Float16)v1.z; a[i][7] = (_Float16)v1.w;
    }
#pragma unroll
    for (int j = 0; j < 4; ++j) {
      int n = n0 + j * 16 + r16;                 // n'
      int rj = (n & 3) * 512 + (n >> 2);         // W_ih row
      const float* p = W_ih + (long)rj * 1024 + ko;
      float4 v0 = *(const float4*)(p);
      float4 v1 = *(const float4*)(p + 4);
      bf[j][0] = (_Float16)v0.x; bf[j][1] = (_Float16)v0.y; bf[j][2] = (_Float16)v0.z; bf[j][3] = (_Float16)v0.w;
      bf[j][4] = (_Float16)v1.x; bf[j][5] = (_Float16)v1.y; bf[j][6] = (_Float16)v1.z; bf[j][7] = (_Float16)v1.w;
    }
#pragma unroll
    for (int i = 0; i < 4; ++i)
#pragma unroll
      for (int j = 0; j < 4; ++j)
        acc[i][j] = __builtin_amdgcn_mfma_f32_16x16x32_f16(a[i], bf[j], acc[i][j], 0, 0, 0);
  }
  __syncthreads();
#pragma unroll
  for (int i = 0; i < 4; ++i) {
    int rl = (wv & 1) * 64 + i * 16 + quad * 4;
#pragma unroll
    for (int r = 0; r < 4; ++r)
#pragma unroll
      for (int j = 0; j < 4; ++j) {
        int cl = (wv >> 1) * 64 + j * 16 + r16;
        ctile[(rl + r) * 136 + cl] = (_Float16)acc[i][j][r];
      }
  }
  __syncthreads();
  _Float16* gembH = (_Float16*)(ws + WS_GEMB);
#pragma unroll
  for (int it = 0; it < 8; ++it) {
    int ch = it * 256 + tid;
    int row = ch >> 4, off = (ch & 15) * 8;
    int grow = mt * 128 + row;
    if (grow < 3136) {
      f16x8 hv = *(f16x8*)(ctile + row * 136 + off);
      *(f16x8*)(gembH + (long)grow * 2048 + nt * 128 + off) = hv;
    }
  }
}

// ---------------- per-step K_A: att2 (dot2) + e + softmax + weights + ctx ----------------
__global__ __launch_bounds__(512) void attn_kernel(float* __restrict__ ws, const float* __restrict__ image,
                                                   const float* __restrict__ W_full, const float* __restrict__ b_full,
                                                   const float* __restrict__ b_dec, float* __restrict__ out, int t) {
  const int* iws = (const int*)ws;
  int b = blockIdx.x;
  if (b >= iws[WS_NB + t]) return;
  __shared__ __align__(16) float wf_s[512], att2_s[512], e_s[200], zred[8];
  __shared__ __align__(16) f16x2 h2_s[256];
  int tid = threadIdx.x;
  int wv = tid >> 6, lane = tid & 63;
  _Float16* xH = (_Float16*)(ws + WS_XH);
  wf_s[tid] = W_full[tid];
  if (tid < 256) h2_s[tid] = ((const f16x2*)xH)[b * 512 + 256 + tid];
  float bd = b_dec[tid];
  __syncthreads();
  // att2[a=tid] = h . W_dec[a] + b_dec[a]  via k-pair dot2, coalesced WDT reads
  {
    const f16x2* wdt = (const f16x2*)(ws + WS_WDT);
    float acc = 0.f;
#pragma unroll 8
    for (int kk = 0; kk < 256; ++kk)
      acc = dot2f(wdt[kk * 512 + tid], h2_s[kk], acc);
    att2_s[tid] = acc + bd;
  }
  __syncthreads();
  // e_p = W_full . relu(enc[p]+att2) + b_full ; e_s[p] = exp(e_p)
  {
    const _Float16* encH = (const _Float16*)(ws + WS_ENCH);
    float at[8], wf[8];
#pragma unroll
    for (int q = 0; q < 8; ++q) { at[q] = att2_s[lane * 8 + q]; wf[q] = wf_s[lane * 8 + q]; }
    float bf0 = b_full[0];
    for (int i = 0; i < 25; ++i) {
      int p = wv + 8 * i;
      if (p < 196) {
        f16x8 ev = *(const f16x8*)(encH + (long)(b * 196 + p) * 512 + lane * 8);
        float acc = fmaxf((float)ev[0] + at[0], 0.f) * wf[0];
#pragma unroll
        for (int q = 1; q < 8; ++q) acc = fmaf(fmaxf((float)ev[q] + at[q], 0.f), wf[q], acc);
        acc = wave_reduce_sum(acc);
        if (lane == 0) e_s[p] = expf(acc + bf0);   // |e| small by construction
      }
    }
  }
  __syncthreads();
  float v = (tid < 196) ? e_s[tid] : 0.f;
  float sr = wave_reduce_sum(v);
  if (lane == 0) zred[wv] = sr;
  __syncthreads();
  float rz = 1.f / (zred[0] + zred[1] + zred[2] + zred[3] + zred[4] + zred[5] + zred[6] + zred[7]);
  if (tid < 196) out[OUT_W + (long)(b * 49 + t) * 196 + tid] = e_s[tid] * rz;
  // ctx[d=tid] = rz * sum_p e_p * feats[p][d]  (coalesced across tid)
  {
    const float* img = image + (long)iws[WS_SORT + b] * 100352;
    float acc = 0.f;
#pragma unroll 4
    for (int c = 0; c < 49; ++c) {
      float4 ev = *(const float4*)(e_s + c * 4);
      acc = fmaf(ev.x, img[(c * 4 + 0) * 512 + tid], acc);
      acc = fmaf(ev.y, img[(c * 4 + 1) * 512 + tid], acc);
      acc = fmaf(ev.z, img[(c * 4 + 2) * 512 + tid], acc);
      acc = fmaf(ev.w, img[(c * 4 + 3) * 512 + tid], acc);
    }
    xH[b * 1024 + tid] = (_Float16)(acc * rz);
  }
}

// ---------------- per-step K_B: gates MFMA (n' order) + fused LSTM ----------------
__global__ __launch_bounds__(256) void gates_lstm_kernel(float* __restrict__ ws,
                                                         const float* __restrict__ b_unused0,
                                                         const float* __restrict__ b_unused1, int t) {
  __shared__ float Gs[64][65];
  const int* iws = (const int*)ws;
  int bn = blockIdx.x;              // 0..31: d range [bn*16, bn*16+16)
  int tid = threadIdx.x;
  int wv = tid >> 6, lane = tid & 63;
  int r16 = lane & 15, quad = lane >> 4;
  const _Float16* xH = (const _Float16*)(ws + WS_XH);
  const _Float16* WgH = (const _Float16*)(ws + WS_WGH);
  int n0 = bn * 64 + wv * 16;       // n' base of this wave
  floatx4 acc[4];
#pragma unroll
  for (int i = 0; i < 4; ++i) acc[i] = (floatx4){0.f, 0.f, 0.f, 0.f};
#pragma unroll 4
  for (int kc = 0; kc < 32; ++kc) {
    int ko = kc * 32 + quad * 8;
    f16x8 b8 = *(const f16x8*)(WgH + (long)(n0 + r16) * 1024 + ko);
#pragma unroll
    for (int i = 0; i < 4; ++i) {
      f16x8 a8 = *(const f16x8*)(xH + (long)(i * 16 + r16) * 1024 + ko);
      acc[i] = __builtin_amdgcn_mfma_f32_16x16x32_f16(a8, b8, acc[i], 0, 0, 0);
    }
  }
#pragma unroll
  for (int i = 0; i < 4; ++i)
#pragma unroll
    for (int r = 0; r < 4; ++r)
      Gs[i * 16 + quad * 4 + r][wv * 16 + r16] = acc[i][r];
  __syncthreads();
  // LSTM: thread u -> m = u&63, dgrp = u>>6 (4 consecutive d's)
  {
    int m = tid & 63, dgrp = tid >> 6;
    int nb = iws[WS_NB + t];
    const _Float16* gembH = (const _Float16*)(ws + WS_GEMB) + ((long)(m * 49 + t)) * 2048 + bn * 64 + dgrp * 16;
    f16x8 g0 = *(const f16x8*)(gembH);
    f16x8 g1 = *(const f16x8*)(gembH + 8);
    const float* bs = ws + WS_BS + bn * 64 + dgrp * 16;
    int d0 = bn * 16 + dgrp * 4;
    float4 cv = *(const float4*)(ws + WS_C + m * 512 + d0);
    float cn4[4], hn4[4];
    float cold[4] = {cv.x, cv.y, cv.z, cv.w};
#pragma unroll
    for (int q = 0; q < 4; ++q) {
      float ge[4];
#pragma unroll
      for (int g = 0; g < 4; ++g) {
        int nl = q * 4 + g;
        float gv = (nl < 8) ? (float)g0[nl] : (float)g1[nl - 8];
        ge[g] = Gs[m][dgrp * 16 + nl] + gv + bs[nl];
      }
      float cn = sigm(ge[1]) * cold[q] + sigm(ge[0]) * tanhf(ge[2]);
      float hn = sigm(ge[3]) * tanhf(cn);
      cn4[q] = cn; hn4[q] = hn;
    }
    if (m < nb) {
      *(float4*)(ws + WS_C + m * 512 + d0) = make_float4(cn4[0], cn4[1], cn4[2], cn4[3]);
      f16x4 h4;
      h4[0] = (_Float16)hn4[0]; h4[1] = (_Float16)hn4[1]; h4[2] = (_Float16)hn4[2]; h4[3] = (_Float16)hn4[3];
      *(f16x4*)((_Float16*)(ws + WS_XH) + m * 1024 + 512 + d0) = h4;
      *(f16x4*)((_Float16*)(ws + WS_HALLH) + (long)(iws[WS_ROWOFF + t] + m) * 512 + d0) = h4;
    }
  }
}

// ---------------- W_score fp32 -> fp16 (overlay) ----------------
__global__ void w2h_kernel(const float* __restrict__ W, float* __restrict__ ws) {
  _Float16* dst = (_Float16*)(ws + WS_WSH);
  int i = blockIdx.x * 256 + threadIdx.x;   // 1,280,000 float4s
  if (i < 1280000) {
    float4 v = ((const float4*)W)[i];
    f16x4 h;
    h[0] = (_Float16)v.x; h[1] = (_Float16)v.y; h[2] = (_Float16)v.z; h[3] = (_Float16)v.w;
    *(f16x4*)(dst + i * 4) = h;
  }
}

// ---------------- scores = HALL(fp16) @ W_score(fp16)^T + b_score (MFMA) ----------------
__global__ __launch_bounds__(256) void score_mfma_kernel(const float* __restrict__ ws,
                                                         const float* __restrict__ b_score,
                                                         float* __restrict__ out) {
  const int* iws = (const int*)ws;
  int R = iws[WS_NB + 49];
  int mt = blockIdx.x, nt = blockIdx.y;
  if (mt * 128 >= R) return;
  int tid = threadIdx.x;
  int wv = tid >> 6, lane = tid & 63;
  int m0 = mt * 128 + (wv & 1) * 64;
  int n0 = nt * 128 + (wv >> 1) * 64;
  int r16 = lane & 15, quad = lane >> 4;
  const _Float16* AH = (const _Float16*)(ws + WS_HALLH);
  const _Float16* BH = (const _Float16*)(ws + WS_WSH);
  floatx4 acc[4][4];
#pragma unroll
  for (int i = 0; i < 4; ++i)
#pragma unroll
    for (int j = 0; j < 4; ++j) acc[i][j] = (floatx4){0.f, 0.f, 0.f, 0.f};
#pragma unroll 4
  for (int kc = 0; kc < 16; ++kc) {
    int ko = kc * 32 + quad * 8;
    f16x8 a[4], b[4];
#pragma unroll
    for (int i = 0; i < 4; ++i) a[i] = *(const f16x8*)(AH + (long)(m0 + i * 16 + r16) * 512 + ko);
#pragma unroll
    for (int j = 0; j < 4; ++j) b[j] = *(const f16x8*)(BH + (long)(n0 + j * 16 + r16) * 512 + ko);
#pragma unroll
    for (int i = 0; i < 4; ++i)
#pragma unroll
      for (int j = 0; j < 4; ++j)
        acc[i][j] = __builtin_amdgcn_mfma_f32_16x16x32_f16(a[i], b[j], acc[i][j], 0, 0, 0);
  }
#pragma unroll
  for (int i = 0; i < 4; ++i) {
    int rbase = m0 + i * 16 + quad * 4;
#pragma unroll
    for (int r = 0; r < 4; ++r) {
      int grow = rbase + r;
      if (grow < R) {
        int tb = iws[WS_RMAP + grow];
        long obase = (long)(tb & 63) * 490000 + (long)(tb >> 6) * 10000;
#pragma unroll
        for (int j = 0; j < 4; ++j) {
          int col = n0 + j * 16 + r16;
          if (col < 10000) out[obase + col] = acc[i][j][r] + b_score[col];
        }
      }
    }
  }
}

// ---------------- launch ----------------
extern "C" void kernel_launch(void* const* d_in, const int* in_sizes, int n_in,
                              void* d_out, int out_size, void* d_ws, size_t ws_size,
                              hipStream_t stream) {
  const float* image   = (const float*)d_in[0];
  const int*   caps    = (const int*)d_in[1];
  const int*   caplens = (const int*)d_in[2];
  const float* emb     = (const float*)d_in[3];
  const float* W_ih    = (const float*)d_in[4];
  const float* W_hh    = (const float*)d_in[5];
  const float* b_ih    = (const float*)d_in[6];
  const float* b_hh    = (const float*)d_in[7];
  const float* W_enc   = (const float*)d_in[8];
  const float* b_enc   = (const float*)d_in[9];
  const float* W_dec   = (const float*)d_in[10];
  const float* b_dec   = (const float*)d_in[11];
  const float* W_full  = (const float*)d_in[12];
  const float* b_full  = (const float*)d_in[13];
  const float* W_score = (const float*)d_in[14];
  const float* b_score = (const float*)d_in[15];
  float* out = (float*)d_out;
  float* ws  = (float*)d_ws;

  setup_kernel<<<1, 64, 0, stream>>>(caps, caplens, ws, out);
  zero_kernel<<<3200, 256, 0, stream>>>(out, ws);
  wdecT_kernel<<<dim3(8, 8), 256, 0, stream>>>(W_dec, ws);
  wgh_kernel<<<2048, 256, 0, stream>>>(W_ih, W_hh, b_ih, b_hh, ws);
  encatt_kernel<<<dim3(98, 4), 256, 0, stream>>>(image, W_enc, b_enc, ws);
  embgates_kernel<<<dim3(25, 16), 256, 0, stream>>>(ws, emb, W_ih);
  for (int t = 0; t < 49; ++t) {
    attn_kernel<<<64, 512, 0, stream>>>(ws, image, W_full, b_full, b_dec, out, t);
    gates_lstm_kernel<<<32, 256, 0, stream>>>(ws, b_ih, b_hh, t);
  }
  w2h_kernel<<<5000, 256, 0, stream>>>(W_score, ws);
  score_mfma_kernel<<<dim3(25, 79), 256, 0, stream>>>(ws, b_score, out);
}